// Round 14
// baseline (349.132 us; speedup 1.0000x reference)
//
#include <hip/hip_runtime.h>
#include <hip/hip_bf16.h>
#include <hip/hip_fp16.h>

#define N_TRAIN 200000
#define DIMS    64
#define NQ      1024
#define KSEL    32
#define NCLS    10

#define CHR     192     // rows per filter chunk
#define NCH     1048    // 8 XCD groups x 131 chunks; 1048*192 >= 200000
#define LCAP    4       // pool slots per (chunk, query)
#define SENT    0xFFFFFFFFu
#define OVFCAP  256     // per-query overflow cap
#define TOTC    4096    // merge candidate cap per query
#define MAXS    1536    // merge survivor cap per query
#define SAMPLES 4096    // threshold sample rows (0..4095)
#define NPB     3125    // k_prep blocks

typedef float f32x4 __attribute__((ext_vector_type(4)));
typedef short f16x8 __attribute__((ext_vector_type(8)));

__device__ __forceinline__ unsigned fmap(float f) {
    unsigned u = __float_as_uint(f);
    return u ^ ((u >> 31) ? 0xFFFFFFFFu : 0x80000000u);
}
__device__ __forceinline__ float funmap(unsigned m) {
    unsigned u = m ^ ((m >> 31) ? 0x80000000u : 0xFFFFFFFFu);
    return __uint_as_float(u);
}
__device__ __forceinline__ unsigned short f2h(float f) {   // RNE f32->f16 bits
    union { __half h; unsigned short u; } c;
    c.h = __float2half_rn(f);
    return c.u;
}
__device__ __forceinline__ f16x8 pack8h(float4 a, float4 b) {
    f16x8 r;
    r[0] = (short)f2h(a.x); r[1] = (short)f2h(a.y);
    r[2] = (short)f2h(a.z); r[3] = (short)f2h(a.w);
    r[4] = (short)f2h(b.x); r[5] = (short)f2h(b.y);
    r[6] = (short)f2h(b.z); r[7] = (short)f2h(b.w);
    return r;
}

// ---------------- fused: x2 = ||x||^2, per-block max, X -> f16 (one X read)
__global__ __launch_bounds__(512) void k_prep(const float* __restrict__ X,
                                              float* __restrict__ x2,
                                              float* __restrict__ bmax,
                                              short* __restrict__ Xh) {
    int T = blockIdx.x * 512 + threadIdx.x;   // 8 threads per row
    int row = T >> 3;
    int l8 = T & 7;
    const float4* xp = (const float4*)(X + (long)row * 64 + l8 * 8);
    float4 a = xp[0], b = xp[1];
    *(f16x8*)(Xh + (long)row * 64 + l8 * 8) = pack8h(a, b);
    float p = a.x * a.x + a.y * a.y + a.z * a.z + a.w * a.w +
              b.x * b.x + b.y * b.y + b.z * b.z + b.w * b.w;
    p += __shfl_xor(p, 1);
    p += __shfl_xor(p, 2);
    p += __shfl_xor(p, 4);
    if (l8 == 0) x2[row] = p;
    float m = p;
    m = fmaxf(m, __shfl_xor(m, 8));
    m = fmaxf(m, __shfl_xor(m, 16));
    m = fmaxf(m, __shfl_xor(m, 32));
    __shared__ float wm[8];
    if ((threadIdx.x & 63) == 0) wm[threadIdx.x >> 6] = m;
    __syncthreads();
    if (threadIdx.x == 0) {
        float r = wm[0];
#pragma unroll
        for (int i = 1; i < 8; i++) r = fmaxf(r, wm[i]);
        bmax[blockIdx.x] = r;
    }
}

__global__ __launch_bounds__(256) void k_max(const float* __restrict__ bmax,
                                             float* __restrict__ x2maxf) {
    float m = -1e30f;
    for (int i = threadIdx.x; i < NPB; i += 256) m = fmaxf(m, bmax[i]);
#pragma unroll
    for (int d = 1; d < 64; d <<= 1) m = fmaxf(m, __shfl_xor(m, d));
    __shared__ float wm[4];
    if ((threadIdx.x & 63) == 0) wm[threadIdx.x >> 6] = m;
    __syncthreads();
    if (threadIdx.x == 0)
        *x2maxf = fmaxf(fmaxf(wm[0], wm[1]), fmaxf(wm[2], wm[3]));
}

// ---------------- Q f32 -> f16
__global__ __launch_bounds__(256) void k_cvt(const float* __restrict__ src,
                                             short* __restrict__ dst) {
    long c = (long)blockIdx.x * 256 + threadIdx.x;
    const float4* xp = (const float4*)(src + c * 8);
    float4 a = xp[0], b = xp[1];
    *(f16x8*)(dst + c * 8) = pack8h(a, b);
}

// ---------------- fused sampling + threshold: exact f32 keys for rows
// 0..4095 computed in-block (coalesced, 4 lanes/row), bisect 32nd smallest,
// widen by f16 filter error bound.
__global__ __launch_bounds__(256) void k_sel(const float* __restrict__ X,
                                             const float* __restrict__ Qm,
                                             const float* __restrict__ x2,
                                             const float* __restrict__ x2maxf,
                                             float* __restrict__ tqw,
                                             float* __restrict__ q2g) {
    int q = blockIdx.x, tid = threadIdx.x;
    __shared__ float qs[64];
    __shared__ unsigned skey[SAMPLES];   // 16 KB
    __shared__ float q2s_;
    __shared__ int cnt;

    if (tid < 64) qs[tid] = Qm[(long)q * 64 + tid];
    __syncthreads();
    if (tid < 64) {
        float v = qs[tid];
        float p = v * v;
#pragma unroll
        for (int d = 1; d < 64; d <<= 1) p += __shfl_xor(p, d);
        if (tid == 0) q2s_ = p;
    }

    // per-lane quarter of the query row (runtime l4 index into LDS is fine)
    int l4 = tid & 3;
    float4 qf[4];
#pragma unroll
    for (int k = 0; k < 4; k++) qf[k] = ((const float4*)qs)[l4 * 4 + k];

    // phase A: 64 rows per iteration, 4 lanes per row (fully coalesced)
    for (int it = 0; it < SAMPLES / 64; it++) {
        int row = (it << 6) + (tid >> 2);
        const float4* xr = (const float4*)(X + (long)row * 64 + l4 * 16);
        float dot = 0.f;
#pragma unroll
        for (int k = 0; k < 4; k++) {
            float4 xv = xr[k];
            dot += qf[k].x * xv.x + qf[k].y * xv.y + qf[k].z * xv.z + qf[k].w * xv.w;
        }
        dot += __shfl_xor(dot, 1);
        dot += __shfl_xor(dot, 2);
        if (l4 == 0) skey[row] = fmap(x2[row] - 2.f * dot);
    }
    __syncthreads();

    // phase B: bisect exact 32nd-smallest mapped key among 4096 samples
    unsigned mk[SAMPLES / 256];
#pragma unroll
    for (int m = 0; m < SAMPLES / 256; m++) mk[m] = skey[tid + 256 * m];
    unsigned lo = 0u, hi = 0xFFFFFFFFu;
    for (int itb = 0; itb < 32; ++itb) {
        __syncthreads();
        if (tid == 0) cnt = 0;
        __syncthreads();
        unsigned mid = lo + ((hi - lo) >> 1);
        int c = 0;
#pragma unroll
        for (int m = 0; m < SAMPLES / 256; m++) c += (mk[m] <= mid) ? 1 : 0;
#pragma unroll
        for (int d = 1; d < 64; d <<= 1) c += __shfl_xor(c, d);
        if ((tid & 63) == 0) atomicAdd(&cnt, c);
        __syncthreads();
        if (cnt >= KSEL) hi = mid; else lo = mid + 1;
    }
    if (tid == 0) {
        float t = funmap(hi);                // exact 32nd-smallest sample key
        float q2 = q2s_;
        // widen: 2x f16 dot-error bound + margin (same proven inequality)
        tqw[q] = t + 0.004f * sqrtf(q2 * (*x2maxf)) + 0.1f;
        q2g[q] = q2;
    }
}

// ================================================================ k_dist
// Filter pass (identical to R13 MODE0, proven): single-wave blocks,
// XCD-aware mapping, 128 queries/wave, depth-1 register prefetch,
// LDS pools -> sentinel-coded uint4 flush.
__global__ __launch_bounds__(64) void k_dist(
    const short* __restrict__ Xh, const short* __restrict__ Qh,
    const float* __restrict__ x2, const float* __restrict__ tqw,
    unsigned* __restrict__ pool,
    unsigned* __restrict__ ovfcnt, uint2* __restrict__ ovf) {
    int bid = blockIdx.x;
    int xcd = bid & 7;
    int j = bid >> 3;
    int cb = xcd * 131 + (j >> 3);
    int qt = j & 7;
    int lane = threadIdx.x;     // 0..63
    int lr = lane & 15;
    int lk = lane >> 4;

    __shared__ unsigned lcnt[128];
    __shared__ unsigned lbuf[128 * LCAP];

    int r0 = cb * CHR;
    int rowEnd = min(r0 + CHR, N_TRAIN);

    lcnt[lane] = 0u;
    lcnt[lane + 64] = 0u;
    __syncthreads();

    int qbase = qt << 7;        // 128 queries

    f16x8 afr[8][2];
#pragma unroll
    for (int qi = 0; qi < 8; qi++) {
        const short* qp = Qh + (long)(qbase + (qi << 4) + lr) * 64 + (lk << 3);
        afr[qi][0] = *(const f16x8*)qp;
        afr[qi][1] = *(const f16x8*)(qp + 32);
    }
    float htq[8];
#pragma unroll
    for (int qi = 0; qi < 8; qi++) {
        float4 t4 = *(const float4*)(tqw + qbase + (qi << 4) + (lk << 2));
        htq[qi] = 0.5f * fmaxf(fmaxf(t4.x, t4.y), fmaxf(t4.z, t4.w));
    }

    // depth-1 register prefetch over 16-row groups
    f16x8 cb0, cb1;
    float cx2;
    {
        int rowc = min(r0 + lr, rowEnd - 1);
        const short* xp = Xh + (long)rowc * 64 + (lk << 3);
        cb0 = *(const f16x8*)xp;
        cb1 = *(const f16x8*)(xp + 32);
        cx2 = (r0 + lr < rowEnd) ? x2[rowc] : 1e30f;
    }

    for (int base = r0; base < rowEnd; base += 16) {
        f16x8 b0 = cb0, b1 = cb1;
        float x2c = cx2;
        int nb = base + 16;
        if (nb < rowEnd) {
            int rowc = min(nb + lr, rowEnd - 1);
            const short* xp = Xh + (long)rowc * 64 + (lk << 3);
            cb0 = *(const f16x8*)xp;
            cb1 = *(const f16x8*)(xp + 32);
            cx2 = (nb + lr < rowEnd) ? x2[rowc] : 1e30f;
        }
        int row = base + lr;
        bool valid = row < rowEnd;
        float hx = 0.5f * x2c;

#pragma unroll
        for (int qi = 0; qi < 8; qi++) {
            f32x4 acc = {0.f, 0.f, 0.f, 0.f};
            acc = __builtin_amdgcn_mfma_f32_16x16x32_f16(afr[qi][0], b0, acc, 0, 0, 0);
            acc = __builtin_amdgcn_mfma_f32_16x16x32_f16(afr[qi][1], b1, acc, 0, 0, 0);
            float mx = fmaxf(fmaxf(acc[0], acc[1]), fmaxf(acc[2], acc[3]));
            if (valid && mx >= hx - htq[qi]) {     // sound quick reject
                float4 t4 = *(const float4*)(tqw + qbase + (qi << 4) + (lk << 2));
                float tq4[4] = {t4.x, t4.y, t4.z, t4.w};
#pragma unroll
                for (int r4 = 0; r4 < 4; r4++) {
                    if (acc[r4] >= hx - 0.5f * tq4[r4]) {
                        int ql = (qi << 4) + (lk << 2) + r4;     // 0..127
                        int qg = qbase + ql;
                        // 24-bit approx key + 8-bit local row (<192)
                        unsigned entry = (fmap(x2c - 2.f * acc[r4]) & 0xFFFFFF00u) |
                                         (unsigned)(row - r0);
                        unsigned slot = atomicAdd(&lcnt[ql], 1u);
                        if (slot < LCAP) {
                            lbuf[ql * LCAP + slot] = entry;
                        } else {   // rare overflow: per-query global pool
                            unsigned o = atomicAdd(&ovfcnt[qg], 1u);
                            if (o < OVFCAP)
                                ovf[qg * OVFCAP + o] =
                                    make_uint2(entry >> 8, (unsigned)row);
                        }
                    }
                }
            }
        }
    }

    // sentinel-coded flush: one uint4 per query, no global atomics
    __syncthreads();
#pragma unroll
    for (int j2 = 0; j2 < 2; j2++) {
        int ql = (j2 << 6) + lane;
        unsigned lc = min(lcnt[ql], (unsigned)LCAP);
        uint4 v;
        v.x = (lc > 0) ? lbuf[ql * LCAP + 0] : SENT;
        v.y = (lc > 1) ? lbuf[ql * LCAP + 1] : SENT;
        v.z = (lc > 2) ? lbuf[ql * LCAP + 2] : SENT;
        v.w = (lc > 3) ? lbuf[ql * LCAP + 3] : SENT;
        *(uint4*)&pool[((long)cb * NQ + qbase + ql) * LCAP] = v;
    }
}

// ---------------- approx-cut (24-bit) -> exact re-rank survivors -> vote
__global__ __launch_bounds__(256) void k_merge(const float* __restrict__ Qm,
                                               const float* __restrict__ X,
                                               const float* __restrict__ x2,
                                               const int* __restrict__ labels,
                                               const unsigned* __restrict__ pool,
                                               const unsigned* __restrict__ ovfcnt,
                                               const uint2* __restrict__ ovf,
                                               const float* __restrict__ q2g,
                                               const float* __restrict__ x2maxf,
                                               int* __restrict__ out) {
    int q = blockIdx.x, tid = threadIdx.x;
    __shared__ unsigned eK[TOTC];        // 24-bit approx keys
    __shared__ int eR[TOTC];
    __shared__ int sR[MAXS];
    __shared__ float sKey[MAXS];
    __shared__ int sLab[MAXS];
    __shared__ float qs[64];
    __shared__ int tot, cnt, ns, nw, nt;
    __shared__ unsigned cutS;
    __shared__ float wKey[34];
    __shared__ int wLab[34];
    __shared__ int tIdx[64];
    __shared__ int tLab[64];

    if (tid == 0) { tot = 0; ns = 0; nw = 0; nt = 0; }
    if (tid < 64) qs[tid] = Qm[(long)q * 64 + tid];
    __syncthreads();

    // gather from sentinel-coded pools
    for (int c2 = tid; c2 < NCH; c2 += 256) {
        uint4 v = *(const uint4*)&pool[((long)c2 * NQ + q) * LCAP];
        int rbase = c2 * CHR;
        if (v.x != SENT) { int p = atomicAdd(&tot, 1); if (p < TOTC) { eK[p] = v.x >> 8; eR[p] = rbase + (int)(v.x & 255u); } }
        if (v.y != SENT) { int p = atomicAdd(&tot, 1); if (p < TOTC) { eK[p] = v.y >> 8; eR[p] = rbase + (int)(v.y & 255u); } }
        if (v.z != SENT) { int p = atomicAdd(&tot, 1); if (p < TOTC) { eK[p] = v.z >> 8; eR[p] = rbase + (int)(v.z & 255u); } }
        if (v.w != SENT) { int p = atomicAdd(&tot, 1); if (p < TOTC) { eK[p] = v.w >> 8; eR[p] = rbase + (int)(v.w & 255u); } }
    }
    int ov = min((int)ovfcnt[q], OVFCAP);
    for (int i = tid; i < ov; i += 256) {
        uint2 e = ovf[q * OVFCAP + i];
        int p = atomicAdd(&tot, 1);
        if (p < TOTC) { eK[p] = e.x; eR[p] = (int)e.y; }
    }
    __syncthreads();
    int T = min(tot, TOTC);

    // bisect 24-bit approx keys for the 32nd smallest
    unsigned mk[16];
#pragma unroll
    for (int m = 0; m < 16; m++) { int i = tid + (m << 8); mk[m] = (i < T) ? eK[i] : 0xFFFFFFFFu; }
    unsigned lo = 0, hi = 0xFFFFFFu;
    for (int it = 0; it < 24; ++it) {
        __syncthreads();
        if (tid == 0) cnt = 0;
        __syncthreads();
        unsigned mid = (lo + hi) >> 1;
        int c = 0;
#pragma unroll
        for (int m = 0; m < 16; m++) c += (mk[m] <= mid) ? 1 : 0;
#pragma unroll
        for (int d = 1; d < 64; d <<= 1) c += __shfl_xor(c, d);
        if ((tid & 63) == 0) atomicAdd(&cnt, c);
        __syncthreads();
        if (cnt >= KSEL) hi = mid; else lo = mid + 1;
    }
    float q2v = q2g[q];
    if (tid == 0) {
        unsigned vv = min(hi + 1u, 0xFFFFFFu);
        float tf = funmap(vv << 8);
        float err = 0.004f * sqrtf(q2v * (*x2maxf)) + 0.1f;   // 2x f16 key error + margin
        cutS = min((fmap(tf + err) >> 8) + 1u, 0xFFFFFFu);
    }
    __syncthreads();
    unsigned cut = cutS;
    for (int i = tid; i < T; i += 256)
        if (eK[i] <= cut) { int p = atomicAdd(&ns, 1); if (p < MAXS) sR[p] = eR[i]; }
    __syncthreads();
    int NS = min(ns, MAXS);

    // exact fp32 re-rank of survivors
    for (int i = tid; i < NS; i += 256) {
        int row = sR[i];
        const float4* xr = (const float4*)(X + (long)row * 64);
        const float4* qr = (const float4*)qs;
        float dot = 0.f;
#pragma unroll
        for (int k4 = 0; k4 < 16; k4++) {
            float4 xv = xr[k4], qv = qr[k4];
            dot += qv.x * xv.x + qv.y * xv.y + qv.z * xv.z + qv.w * xv.w;
        }
        sKey[i] = x2[row] - 2.f * dot;
        sLab[i] = labels[row];
    }
    __syncthreads();

    // exact 32nd smallest among survivors (32-step bisection)
    unsigned uk[6];
#pragma unroll
    for (int m = 0; m < 6; m++) { int i = tid + (m << 8); uk[m] = (i < NS) ? fmap(sKey[i]) : 0xFFFFFFFFu; }
    unsigned lo2 = 0u, hi2 = 0xFFFFFFFFu;
    for (int it = 0; it < 32; ++it) {
        __syncthreads();
        if (tid == 0) cnt = 0;
        __syncthreads();
        unsigned mid = lo2 + ((hi2 - lo2) >> 1);
        int c = 0;
#pragma unroll
        for (int m = 0; m < 6; m++) c += (uk[m] <= mid) ? 1 : 0;
#pragma unroll
        for (int d = 1; d < 64; d <<= 1) c += __shfl_xor(c, d);
        if ((tid & 63) == 0) atomicAdd(&cnt, c);
        __syncthreads();
        if (cnt >= KSEL) hi2 = mid; else lo2 = mid + 1;
    }
    unsigned T32 = hi2;   // count(<T32) <= 31, count(<=T32) >= 32

#pragma unroll
    for (int m = 0; m < 6; m++) {
        int i = tid + (m << 8);
        if (i < NS) {
            if (uk[m] < T32) {
                int p = atomicAdd(&nw, 1);
                if (p < 34) { wKey[p] = sKey[i]; wLab[p] = sLab[i]; }
            } else if (uk[m] == T32) {
                int p = atomicAdd(&nt, 1);
                if (p < 64) { tIdx[p] = sR[i]; tLab[p] = sLab[i]; }
            }
        }
    }
    __syncthreads();

    if (tid == 0) {
        float votes[NCLS] = {0.f, 0.f, 0.f, 0.f, 0.f, 0.f, 0.f, 0.f, 0.f, 0.f};
        int NW = min(nw, 32);
        for (int i = 0; i < NW; i++) {
            float dist = q2v + wKey[i];
            if (dist < 0.f) dist = 0.f;
            if (dist == 0.f) dist = 0.1f;
            votes[wLab[i]] += 1.f / dist;
        }
        int need = KSEL - NW;
        int NT = min(nt, 64);
        float tkey = funmap(T32);
        float dist = q2v + tkey;
        if (dist < 0.f) dist = 0.f;
        if (dist == 0.f) dist = 0.1f;
        float twgt = 1.f / dist;
        for (int t = 0; t < need && t < NT; t++) {   // ties: smallest index first
            int best = -1, bi = 0x7FFFFFFF;
            for (int u = 0; u < NT; u++)
                if (tIdx[u] < bi) { bi = tIdx[u]; best = u; }
            if (best < 0) break;
            votes[tLab[best]] += twgt;
            tIdx[best] = 0x7FFFFFFF;
        }
        float bv = votes[0];
        int bc = 0;
#pragma unroll
        for (int c = 1; c < NCLS; c++)
            if (votes[c] > bv) { bv = votes[c]; bc = c; }
        out[q] = bc;
    }
}

extern "C" void kernel_launch(void* const* d_in, const int* in_sizes, int n_in,
                              void* d_out, int out_size, void* d_ws, size_t ws_size,
                              hipStream_t stream) {
    const float* Qm = (const float*)d_in[0];
    const float* X = (const float*)d_in[1];
    const int* labels = (const int*)d_in[2];
    char* ws = (char*)d_ws;
    // ws layout (end = 45,823,552 B; proven ws_size >= 52,017,408):
    // [0,800000)            x2     float[200000]
    // [800000,804096)       tqw    float[1024]
    // [804096,808192)       q2g    float[1024]
    // [808192,808196)       x2maxf float
    // [808256,820756)       bmax   float[3125]
    // [820800,824896)       ovfcnt u32[1024]
    // [824896,2922048)      ovf    uint2[1024*256]
    // [2922048,20092480)    pool   u32[1048*1024*4]
    // [20092480,45692480)   Xh f16[200000*64]
    // [45692480,45823552)   Qh f16[1024*64]
    float* x2 = (float*)(ws + 0);
    float* tqw = (float*)(ws + 800000);
    float* q2g = (float*)(ws + 804096);
    float* x2maxf = (float*)(ws + 808192);
    float* bmax = (float*)(ws + 808256);
    unsigned* ovfcnt = (unsigned*)(ws + 820800);
    uint2* ovf = (uint2*)(ws + 824896);
    unsigned* pool = (unsigned*)(ws + 2922048);
    short* Xh = (short*)(ws + 20092480);
    short* Qh = (short*)(ws + 45692480);
    int* out = (int*)d_out;

    hipMemsetAsync(ovfcnt, 0, 4096, stream);
    k_prep<<<NPB, 512, 0, stream>>>(X, x2, bmax, Xh);
    k_max<<<1, 256, 0, stream>>>(bmax, x2maxf);
    k_cvt<<<32, 256, 0, stream>>>(Qm, Qh);
    k_sel<<<NQ, 256, 0, stream>>>(X, Qm, x2, x2maxf, tqw, q2g);
    k_dist<<<8 * NCH, 64, 0, stream>>>(Xh, Qh, x2, tqw, pool, ovfcnt, ovf);
    k_merge<<<NQ, 256, 0, stream>>>(Qm, X, x2, labels, pool, ovfcnt, ovf, q2g, x2maxf, out);
}

// Round 15
// 342.248 us; speedup vs baseline: 1.0201x; 1.0201x over previous
//
#include <hip/hip_runtime.h>
#include <hip/hip_bf16.h>
#include <hip/hip_fp16.h>

#define N_TRAIN 200000
#define DIMS    64
#define NQ      1024
#define KSEL    32
#define NCLS    10

#define CHR     192     // rows per filter chunk (12 groups of 16)
#define NCH     1048    // 8 XCD groups x 131 chunks
#define NPAD    201216  // NCH*CHR padded row count
#define LCAP    4       // pool slots per (chunk, query)
#define SENT    0xFFFFFFFFu
#define OVFCAP  256     // per-query overflow cap
#define TOTC    4096    // merge candidate cap per query
#define MAXS    1536    // merge survivor cap per query
#define SAMPLES 8192    // threshold sample rows (0..8191)
#define NPB     3125    // k_prep blocks

typedef float f32x4 __attribute__((ext_vector_type(4)));
typedef short f16x8 __attribute__((ext_vector_type(8)));

__device__ __forceinline__ unsigned fmap(float f) {
    unsigned u = __float_as_uint(f);
    return u ^ ((u >> 31) ? 0xFFFFFFFFu : 0x80000000u);
}
__device__ __forceinline__ float funmap(unsigned m) {
    unsigned u = m ^ ((m >> 31) ? 0x80000000u : 0xFFFFFFFFu);
    return __uint_as_float(u);
}
__device__ __forceinline__ unsigned short f2h(float f) {   // RNE f32->f16 bits
    union { __half h; unsigned short u; } c;
    c.h = __float2half_rn(f);
    return c.u;
}
__device__ __forceinline__ float h2f(short s) {
    return __half2float(*reinterpret_cast<const __half*>(&s));
}
__device__ __forceinline__ f16x8 pack8h(float4 a, float4 b) {
    f16x8 r;
    r[0] = (short)f2h(a.x); r[1] = (short)f2h(a.y);
    r[2] = (short)f2h(a.z); r[3] = (short)f2h(a.w);
    r[4] = (short)f2h(b.x); r[5] = (short)f2h(b.y);
    r[6] = (short)f2h(b.z); r[7] = (short)f2h(b.w);
    return r;
}

// ---------------- fused: x2 = ||x||^2, per-block max, X -> f16 (one X read)
__global__ __launch_bounds__(512) void k_prep(const float* __restrict__ X,
                                              float* __restrict__ x2,
                                              float* __restrict__ bmax,
                                              short* __restrict__ Xh) {
    int T = blockIdx.x * 512 + threadIdx.x;   // 8 threads per row
    int row = T >> 3;
    int l8 = T & 7;
    const float4* xp = (const float4*)(X + (long)row * 64 + l8 * 8);
    float4 a = xp[0], b = xp[1];
    *(f16x8*)(Xh + (long)row * 64 + l8 * 8) = pack8h(a, b);
    float p = a.x * a.x + a.y * a.y + a.z * a.z + a.w * a.w +
              b.x * b.x + b.y * b.y + b.z * b.z + b.w * b.w;
    p += __shfl_xor(p, 1);
    p += __shfl_xor(p, 2);
    p += __shfl_xor(p, 4);
    if (l8 == 0) x2[row] = p;
    float m = p;
    m = fmaxf(m, __shfl_xor(m, 8));
    m = fmaxf(m, __shfl_xor(m, 16));
    m = fmaxf(m, __shfl_xor(m, 32));
    __shared__ float wm[8];
    if ((threadIdx.x & 63) == 0) wm[threadIdx.x >> 6] = m;
    __syncthreads();
    if (threadIdx.x == 0) {
        float r = wm[0];
#pragma unroll
        for (int i = 1; i < 8; i++) r = fmaxf(r, wm[i]);
        bmax[blockIdx.x] = r;
    }
}

// ---------------- reduce bmax; also fill x2 pad rows with 1e30
__global__ __launch_bounds__(256) void k_max(const float* __restrict__ bmax,
                                             float* __restrict__ x2maxf,
                                             float* __restrict__ x2) {
    for (int i = threadIdx.x; i < NPAD - N_TRAIN; i += 256)
        x2[N_TRAIN + i] = 1e30f;
    float m = -1e30f;
    for (int i = threadIdx.x; i < NPB; i += 256) m = fmaxf(m, bmax[i]);
#pragma unroll
    for (int d = 1; d < 64; d <<= 1) m = fmaxf(m, __shfl_xor(m, d));
    __shared__ float wm[4];
    if ((threadIdx.x & 63) == 0) wm[threadIdx.x >> 6] = m;
    __syncthreads();
    if (threadIdx.x == 0)
        *x2maxf = fmaxf(fmaxf(wm[0], wm[1]), fmaxf(wm[2], wm[3]));
}

// ---------------- Q f32 -> f16
__global__ __launch_bounds__(256) void k_cvt(const float* __restrict__ src,
                                             short* __restrict__ dst) {
    long c = (long)blockIdx.x * 256 + threadIdx.x;
    const float4* xp = (const float4*)(src + c * 8);
    float4 a = xp[0], b = xp[1];
    *(f16x8*)(dst + c * 8) = pack8h(a, b);
}

// ---------------- fused sampling + threshold from f16 inputs (8192 rows).
// u16-grid keys in LDS; bisect 32nd smallest; widen hi+2 grid + f16 bound.
__global__ __launch_bounds__(256) void k_sel(const short* __restrict__ Xh,
                                             const short* __restrict__ Qh,
                                             const float* __restrict__ Qm,
                                             const float* __restrict__ x2,
                                             const float* __restrict__ x2maxf,
                                             float* __restrict__ tqw,
                                             float* __restrict__ q2g) {
    int q = blockIdx.x, tid = threadIdx.x;
    __shared__ unsigned short skey[SAMPLES];   // 16 KB
    __shared__ float q2s_;
    __shared__ int cnt;

    if (tid < 64) {
        float v = Qm[(long)q * 64 + tid];
        float p = v * v;
#pragma unroll
        for (int d = 1; d < 64; d <<= 1) p += __shfl_xor(p, d);
        if (tid == 0) q2s_ = p;
    }

    int half = tid & 1;          // two lanes per row, 32 dims each
    float qf[32];
#pragma unroll
    for (int k = 0; k < 4; k++) {
        f16x8 qv = *(const f16x8*)(Qh + (long)q * 64 + (half << 5) + (k << 3));
#pragma unroll
        for (int j = 0; j < 8; j++) qf[(k << 3) + j] = h2f(qv[j]);
    }

    for (int it = 0; it < SAMPLES / 128; it++) {   // 64 iterations
        int row = (it << 7) + (tid >> 1);
        const short* xp = Xh + (long)row * 64 + (half << 5);
        float dot = 0.f;
#pragma unroll
        for (int k = 0; k < 4; k++) {
            f16x8 xv = *(const f16x8*)(xp + (k << 3));
#pragma unroll
            for (int j = 0; j < 8; j++) dot += qf[(k << 3) + j] * h2f(xv[j]);
        }
        dot += __shfl_xor(dot, 1);
        if (half == 0)
            skey[row] = (unsigned short)(fmap(x2[row] - 2.f * dot) >> 16);
    }
    __syncthreads();

    unsigned short mk[32];
#pragma unroll
    for (int m = 0; m < 32; m++) mk[m] = skey[tid + 256 * m];
    unsigned lo = 0, hi = 65535;
    for (int itb = 0; itb < 16; ++itb) {
        __syncthreads();
        if (tid == 0) cnt = 0;
        __syncthreads();
        unsigned mid = (lo + hi) >> 1;
        int c = 0;
#pragma unroll
        for (int m = 0; m < 32; m++) c += (mk[m] <= mid) ? 1 : 0;
#pragma unroll
        for (int d = 1; d < 64; d <<= 1) c += __shfl_xor(c, d);
        if ((tid & 63) == 0) atomicAdd(&cnt, c);
        __syncthreads();
        if (cnt >= KSEL) hi = mid; else lo = mid + 1;
    }
    if (tid == 0) {
        unsigned vv = hi + 2u; if (vv > 65535u) vv = 65535u;
        float t = funmap(vv << 16);
        float q2 = q2s_;
        tqw[q] = t + 0.004f * sqrtf(q2 * (*x2maxf)) + 0.1f;
        q2g[q] = q2;
    }
}

// ================================================================ k_dist
// Single-wave blocks, XCD-aware mapping, 128 queries/wave. Padded x2/Xh
// (x2=1e30, Xh=0 beyond N_TRAIN) -> NO conditionals in the pipeline:
// all 12 group-x2 preloaded to registers; prefetch is pure loads, so the
// compiler can keep next-group loads in flight across MFMA (counted vmcnt).
__global__ __launch_bounds__(64) void k_dist(
    const short* __restrict__ Xh, const short* __restrict__ Qh,
    const float* __restrict__ x2, const float* __restrict__ tqw,
    unsigned* __restrict__ pool,
    unsigned* __restrict__ ovfcnt, uint2* __restrict__ ovf) {
    int bid = blockIdx.x;
    int xcd = bid & 7;
    int j = bid >> 3;
    int cb = xcd * 131 + (j >> 3);
    int qt = j & 7;
    int lane = threadIdx.x;     // 0..63
    int lr = lane & 15;
    int lk = lane >> 4;

    __shared__ unsigned lcnt[128];
    __shared__ unsigned lbuf[128 * LCAP];

    int r0 = cb * CHR;          // always full CHR rows (padded arrays)

    lcnt[lane] = 0u;
    lcnt[lane + 64] = 0u;
    __syncthreads();

    int qbase = qt << 7;        // 128 queries

    f16x8 afr[8][2];
#pragma unroll
    for (int qi = 0; qi < 8; qi++) {
        const short* qp = Qh + (long)(qbase + (qi << 4) + lr) * 64 + (lk << 3);
        afr[qi][0] = *(const f16x8*)qp;
        afr[qi][1] = *(const f16x8*)(qp + 32);
    }
    float htq[8];
#pragma unroll
    for (int qi = 0; qi < 8; qi++) {
        float4 t4 = *(const float4*)(tqw + qbase + (qi << 4) + (lk << 2));
        htq[qi] = 0.5f * fmaxf(fmaxf(t4.x, t4.y), fmaxf(t4.z, t4.w));
    }
    float gx2[12];              // all group x2 up front (static indexing)
#pragma unroll
    for (int g = 0; g < 12; g++) gx2[g] = x2[r0 + (g << 4) + lr];

    f16x8 cb0, cb1;
    {
        const short* xp = Xh + (long)(r0 + lr) * 64 + (lk << 3);
        cb0 = *(const f16x8*)xp;
        cb1 = *(const f16x8*)(xp + 32);
    }

#pragma unroll
    for (int g = 0; g < 12; g++) {
        f16x8 b0 = cb0, b1 = cb1;
        if (g < 11) {           // pure-load prefetch, no value consumption
            const short* xp = Xh + (long)(r0 + ((g + 1) << 4) + lr) * 64 + (lk << 3);
            cb0 = *(const f16x8*)xp;
            cb1 = *(const f16x8*)(xp + 32);
        }
        float x2c = gx2[g];
        float hx = 0.5f * x2c;
        int row = r0 + (g << 4) + lr;

#pragma unroll
        for (int qi = 0; qi < 8; qi++) {
            f32x4 acc = {0.f, 0.f, 0.f, 0.f};
            acc = __builtin_amdgcn_mfma_f32_16x16x32_f16(afr[qi][0], b0, acc, 0, 0, 0);
            acc = __builtin_amdgcn_mfma_f32_16x16x32_f16(afr[qi][1], b1, acc, 0, 0, 0);
            float mx = fmaxf(fmaxf(acc[0], acc[1]), fmaxf(acc[2], acc[3]));
            if (mx >= hx - htq[qi]) {          // sound quick reject (rare)
                float4 t4 = *(const float4*)(tqw + qbase + (qi << 4) + (lk << 2));
                float tq4[4] = {t4.x, t4.y, t4.z, t4.w};
#pragma unroll
                for (int r4 = 0; r4 < 4; r4++) {
                    if (acc[r4] >= hx - 0.5f * tq4[r4]) {
                        int ql = (qi << 4) + (lk << 2) + r4;     // 0..127
                        int qg = qbase + ql;
                        // 24-bit approx key + 8-bit local row (<192)
                        unsigned entry = (fmap(x2c - 2.f * acc[r4]) & 0xFFFFFF00u) |
                                         (unsigned)(row - r0);
                        unsigned slot = atomicAdd(&lcnt[ql], 1u);
                        if (slot < LCAP) {
                            lbuf[ql * LCAP + slot] = entry;
                        } else {   // rare overflow: per-query global pool
                            unsigned o = atomicAdd(&ovfcnt[qg], 1u);
                            if (o < OVFCAP)
                                ovf[qg * OVFCAP + o] =
                                    make_uint2(entry >> 8, (unsigned)row);
                        }
                    }
                }
            }
        }
    }

    // sentinel-coded flush: one uint4 per query, no global atomics
    __syncthreads();
#pragma unroll
    for (int j2 = 0; j2 < 2; j2++) {
        int ql = (j2 << 6) + lane;
        unsigned lc = min(lcnt[ql], (unsigned)LCAP);
        uint4 v;
        v.x = (lc > 0) ? lbuf[ql * LCAP + 0] : SENT;
        v.y = (lc > 1) ? lbuf[ql * LCAP + 1] : SENT;
        v.z = (lc > 2) ? lbuf[ql * LCAP + 2] : SENT;
        v.w = (lc > 3) ? lbuf[ql * LCAP + 3] : SENT;
        *(uint4*)&pool[((long)cb * NQ + qbase + ql) * LCAP] = v;
    }
}

// ---------------- approx-cut (24-bit) -> exact re-rank survivors -> vote
__global__ __launch_bounds__(256) void k_merge(const float* __restrict__ Qm,
                                               const float* __restrict__ X,
                                               const float* __restrict__ x2,
                                               const int* __restrict__ labels,
                                               const unsigned* __restrict__ pool,
                                               const unsigned* __restrict__ ovfcnt,
                                               const uint2* __restrict__ ovf,
                                               const float* __restrict__ q2g,
                                               const float* __restrict__ x2maxf,
                                               int* __restrict__ out) {
    int q = blockIdx.x, tid = threadIdx.x;
    __shared__ unsigned eK[TOTC];        // 24-bit approx keys
    __shared__ int eR[TOTC];
    __shared__ int sR[MAXS];
    __shared__ float sKey[MAXS];
    __shared__ int sLab[MAXS];
    __shared__ float qs[64];
    __shared__ int tot, cnt, ns, nw, nt;
    __shared__ unsigned cutS;
    __shared__ float wKey[34];
    __shared__ int wLab[34];
    __shared__ int tIdx[64];
    __shared__ int tLab[64];

    if (tid == 0) { tot = 0; ns = 0; nw = 0; nt = 0; }
    if (tid < 64) qs[tid] = Qm[(long)q * 64 + tid];
    __syncthreads();

    // gather from sentinel-coded pools
    for (int c2 = tid; c2 < NCH; c2 += 256) {
        uint4 v = *(const uint4*)&pool[((long)c2 * NQ + q) * LCAP];
        int rbase = c2 * CHR;
        if (v.x != SENT) { int p = atomicAdd(&tot, 1); if (p < TOTC) { eK[p] = v.x >> 8; eR[p] = rbase + (int)(v.x & 255u); } }
        if (v.y != SENT) { int p = atomicAdd(&tot, 1); if (p < TOTC) { eK[p] = v.y >> 8; eR[p] = rbase + (int)(v.y & 255u); } }
        if (v.z != SENT) { int p = atomicAdd(&tot, 1); if (p < TOTC) { eK[p] = v.z >> 8; eR[p] = rbase + (int)(v.z & 255u); } }
        if (v.w != SENT) { int p = atomicAdd(&tot, 1); if (p < TOTC) { eK[p] = v.w >> 8; eR[p] = rbase + (int)(v.w & 255u); } }
    }
    int ov = min((int)ovfcnt[q], OVFCAP);
    for (int i = tid; i < ov; i += 256) {
        uint2 e = ovf[q * OVFCAP + i];
        int p = atomicAdd(&tot, 1);
        if (p < TOTC) { eK[p] = e.x; eR[p] = (int)e.y; }
    }
    __syncthreads();
    int T = min(tot, TOTC);

    // bisect 24-bit approx keys for the 32nd smallest
    unsigned mk[16];
#pragma unroll
    for (int m = 0; m < 16; m++) { int i = tid + (m << 8); mk[m] = (i < T) ? eK[i] : 0xFFFFFFFFu; }
    unsigned lo = 0, hi = 0xFFFFFFu;
    for (int it = 0; it < 24; ++it) {
        __syncthreads();
        if (tid == 0) cnt = 0;
        __syncthreads();
        unsigned mid = (lo + hi) >> 1;
        int c = 0;
#pragma unroll
        for (int m = 0; m < 16; m++) c += (mk[m] <= mid) ? 1 : 0;
#pragma unroll
        for (int d = 1; d < 64; d <<= 1) c += __shfl_xor(c, d);
        if ((tid & 63) == 0) atomicAdd(&cnt, c);
        __syncthreads();
        if (cnt >= KSEL) hi = mid; else lo = mid + 1;
    }
    float q2v = q2g[q];
    if (tid == 0) {
        unsigned vv = min(hi + 1u, 0xFFFFFFu);
        float tf = funmap(vv << 8);
        float err = 0.004f * sqrtf(q2v * (*x2maxf)) + 0.1f;   // 2x f16 key error + margin
        cutS = min((fmap(tf + err) >> 8) + 1u, 0xFFFFFFu);
    }
    __syncthreads();
    unsigned cut = cutS;
    for (int i = tid; i < T; i += 256)
        if (eK[i] <= cut) { int p = atomicAdd(&ns, 1); if (p < MAXS) sR[p] = eR[i]; }
    __syncthreads();
    int NS = min(ns, MAXS);

    // exact fp32 re-rank of survivors
    for (int i = tid; i < NS; i += 256) {
        int row = sR[i];
        const float4* xr = (const float4*)(X + (long)row * 64);
        const float4* qr = (const float4*)qs;
        float dot = 0.f;
#pragma unroll
        for (int k4 = 0; k4 < 16; k4++) {
            float4 xv = xr[k4], qv = qr[k4];
            dot += qv.x * xv.x + qv.y * xv.y + qv.z * xv.z + qv.w * xv.w;
        }
        sKey[i] = x2[row] - 2.f * dot;
        sLab[i] = labels[row];
    }
    __syncthreads();

    // exact 32nd smallest among survivors (32-step bisection)
    unsigned uk[6];
#pragma unroll
    for (int m = 0; m < 6; m++) { int i = tid + (m << 8); uk[m] = (i < NS) ? fmap(sKey[i]) : 0xFFFFFFFFu; }
    unsigned lo2 = 0u, hi2 = 0xFFFFFFFFu;
    for (int it = 0; it < 32; ++it) {
        __syncthreads();
        if (tid == 0) cnt = 0;
        __syncthreads();
        unsigned mid = lo2 + ((hi2 - lo2) >> 1);
        int c = 0;
#pragma unroll
        for (int m = 0; m < 6; m++) c += (uk[m] <= mid) ? 1 : 0;
#pragma unroll
        for (int d = 1; d < 64; d <<= 1) c += __shfl_xor(c, d);
        if ((tid & 63) == 0) atomicAdd(&cnt, c);
        __syncthreads();
        if (cnt >= KSEL) hi2 = mid; else lo2 = mid + 1;
    }
    unsigned T32 = hi2;   // count(<T32) <= 31, count(<=T32) >= 32

#pragma unroll
    for (int m = 0; m < 6; m++) {
        int i = tid + (m << 8);
        if (i < NS) {
            if (uk[m] < T32) {
                int p = atomicAdd(&nw, 1);
                if (p < 34) { wKey[p] = sKey[i]; wLab[p] = sLab[i]; }
            } else if (uk[m] == T32) {
                int p = atomicAdd(&nt, 1);
                if (p < 64) { tIdx[p] = sR[i]; tLab[p] = sLab[i]; }
            }
        }
    }
    __syncthreads();

    if (tid == 0) {
        float votes[NCLS] = {0.f, 0.f, 0.f, 0.f, 0.f, 0.f, 0.f, 0.f, 0.f, 0.f};
        int NW = min(nw, 32);
        for (int i = 0; i < NW; i++) {
            float dist = q2v + wKey[i];
            if (dist < 0.f) dist = 0.f;
            if (dist == 0.f) dist = 0.1f;
            votes[wLab[i]] += 1.f / dist;
        }
        int need = KSEL - NW;
        int NT = min(nt, 64);
        float tkey = funmap(T32);
        float dist = q2v + tkey;
        if (dist < 0.f) dist = 0.f;
        if (dist == 0.f) dist = 0.1f;
        float twgt = 1.f / dist;
        for (int t = 0; t < need && t < NT; t++) {   // ties: smallest index first
            int best = -1, bi = 0x7FFFFFFF;
            for (int u = 0; u < NT; u++)
                if (tIdx[u] < bi) { bi = tIdx[u]; best = u; }
            if (best < 0) break;
            votes[tLab[best]] += twgt;
            tIdx[best] = 0x7FFFFFFF;
        }
        float bv = votes[0];
        int bc = 0;
#pragma unroll
        for (int c = 1; c < NCLS; c++)
            if (votes[c] > bv) { bv = votes[c]; bc = c; }
        out[q] = bc;
    }
}

extern "C" void kernel_launch(void* const* d_in, const int* in_sizes, int n_in,
                              void* d_out, int out_size, void* d_ws, size_t ws_size,
                              hipStream_t stream) {
    const float* Qm = (const float*)d_in[0];
    const float* X = (const float*)d_in[1];
    const int* labels = (const int*)d_in[2];
    char* ws = (char*)d_ws;
    // ws layout (end = 45,984,064 B; proven ws_size >= 52,017,408):
    // [0,804864)            x2     float[201216]  (padded; pad = 1e30)
    // [804864,808960)       tqw    float[1024]
    // [808960,813056)       q2g    float[1024]
    // [813056,813060)       x2maxf float
    // [813120,825620)       bmax   float[3125]
    // [825664,829760)       ovfcnt u32[1024]
    // [829760,2926912)      ovf    uint2[1024*256]
    // [2926912,20097344)    pool   u32[1048*1024*4]
    // [20097344,45852992)   Xh f16[201216*64]  (pad rows zeroed)
    // [45852992,45984064)   Qh f16[1024*64]
    float* x2 = (float*)(ws + 0);
    float* tqw = (float*)(ws + 804864);
    float* q2g = (float*)(ws + 808960);
    float* x2maxf = (float*)(ws + 813056);
    float* bmax = (float*)(ws + 813120);
    unsigned* ovfcnt = (unsigned*)(ws + 825664);
    uint2* ovf = (uint2*)(ws + 829760);
    unsigned* pool = (unsigned*)(ws + 2926912);
    short* Xh = (short*)(ws + 20097344);
    short* Qh = (short*)(ws + 45852992);
    int* out = (int*)d_out;

    hipMemsetAsync(ovfcnt, 0, 4096, stream);
    hipMemsetAsync(Xh + (long)N_TRAIN * 64, 0, (long)(NPAD - N_TRAIN) * 64 * 2, stream);
    k_prep<<<NPB, 512, 0, stream>>>(X, x2, bmax, Xh);
    k_max<<<1, 256, 0, stream>>>(bmax, x2maxf, x2);
    k_cvt<<<32, 256, 0, stream>>>(Qm, Qh);
    k_sel<<<NQ, 256, 0, stream>>>(Xh, Qh, Qm, x2, x2maxf, tqw, q2g);
    k_dist<<<8 * NCH, 64, 0, stream>>>(Xh, Qh, x2, tqw, pool, ovfcnt, ovf);
    k_merge<<<NQ, 256, 0, stream>>>(Qm, X, x2, labels, pool, ovfcnt, ovf, q2g, x2maxf, out);
}

// Round 16
// 270.547 us; speedup vs baseline: 1.2905x; 1.2650x over previous
//
#include <hip/hip_runtime.h>
#include <hip/hip_bf16.h>
#include <hip/hip_fp16.h>

#define N_TRAIN 200000
#define DIMS    64
#define NQ      1024
#define KSEL    32
#define NCLS    10

#define CHR     192     // rows per filter chunk
#define NCH     1048    // 8 XCD groups x 131 chunks; 1048*192 >= 200000
#define LCAP    4       // pool slots per (chunk, query)
#define SENT    0xFFFFFFFFu
#define OVFCAP  256     // per-query overflow cap
#define TOTC    4096    // merge candidate cap per query
#define MAXS    1536    // merge survivor cap per query
#define SAMPLES 8192    // threshold sample rows (0..8191)
#define NPB     3125    // k_prep blocks

typedef float f32x4 __attribute__((ext_vector_type(4)));
typedef short f16x8 __attribute__((ext_vector_type(8)));

__device__ __forceinline__ unsigned fmap(float f) {
    unsigned u = __float_as_uint(f);
    return u ^ ((u >> 31) ? 0xFFFFFFFFu : 0x80000000u);
}
__device__ __forceinline__ float funmap(unsigned m) {
    unsigned u = m ^ ((m >> 31) ? 0x80000000u : 0xFFFFFFFFu);
    return __uint_as_float(u);
}
__device__ __forceinline__ unsigned short f2h(float f) {   // RNE f32->f16 bits
    union { __half h; unsigned short u; } c;
    c.h = __float2half_rn(f);
    return c.u;
}
__device__ __forceinline__ f16x8 pack8h(float4 a, float4 b) {
    f16x8 r;
    r[0] = (short)f2h(a.x); r[1] = (short)f2h(a.y);
    r[2] = (short)f2h(a.z); r[3] = (short)f2h(a.w);
    r[4] = (short)f2h(b.x); r[5] = (short)f2h(b.y);
    r[6] = (short)f2h(b.z); r[7] = (short)f2h(b.w);
    return r;
}

// ---------------- fused: x2 = ||x||^2, per-block max, X -> f16 (one X read)
__global__ __launch_bounds__(512) void k_prep(const float* __restrict__ X,
                                              float* __restrict__ x2,
                                              float* __restrict__ bmax,
                                              short* __restrict__ Xh) {
    int T = blockIdx.x * 512 + threadIdx.x;   // 8 threads per row
    int row = T >> 3;
    int l8 = T & 7;
    const float4* xp = (const float4*)(X + (long)row * 64 + l8 * 8);
    float4 a = xp[0], b = xp[1];
    *(f16x8*)(Xh + (long)row * 64 + l8 * 8) = pack8h(a, b);
    float p = a.x * a.x + a.y * a.y + a.z * a.z + a.w * a.w +
              b.x * b.x + b.y * b.y + b.z * b.z + b.w * b.w;
    p += __shfl_xor(p, 1);
    p += __shfl_xor(p, 2);
    p += __shfl_xor(p, 4);
    if (l8 == 0) x2[row] = p;
    float m = p;
    m = fmaxf(m, __shfl_xor(m, 8));
    m = fmaxf(m, __shfl_xor(m, 16));
    m = fmaxf(m, __shfl_xor(m, 32));
    __shared__ float wm[8];
    if ((threadIdx.x & 63) == 0) wm[threadIdx.x >> 6] = m;
    __syncthreads();
    if (threadIdx.x == 0) {
        float r = wm[0];
#pragma unroll
        for (int i = 1; i < 8; i++) r = fmaxf(r, wm[i]);
        bmax[blockIdx.x] = r;
    }
}

__global__ __launch_bounds__(256) void k_max(const float* __restrict__ bmax,
                                             float* __restrict__ x2maxf) {
    float m = -1e30f;
    for (int i = threadIdx.x; i < NPB; i += 256) m = fmaxf(m, bmax[i]);
#pragma unroll
    for (int d = 1; d < 64; d <<= 1) m = fmaxf(m, __shfl_xor(m, d));
    __shared__ float wm[4];
    if ((threadIdx.x & 63) == 0) wm[threadIdx.x >> 6] = m;
    __syncthreads();
    if (threadIdx.x == 0)
        *x2maxf = fmaxf(fmaxf(wm[0], wm[1]), fmaxf(wm[2], wm[3]));
}

// ---------------- Q f32 -> f16
__global__ __launch_bounds__(256) void k_cvt(const float* __restrict__ src,
                                             short* __restrict__ dst) {
    long c = (long)blockIdx.x * 256 + threadIdx.x;
    const float4* xp = (const float4*)(src + c * 8);
    float4 a = xp[0], b = xp[1];
    *(f16x8*)(dst + c * 8) = pack8h(a, b);
}

// ================================================================ k_samp
// Sample-key GEMM with COALESCED key writes. 512 single-wave blocks:
// qt = bid & 7 (128 queries), rb = bid >> 3 (128 sample rows). All 128x128
// u16 keys staged in LDS ([128][132] padded -> conflict-free per-instr
// banks), then ONE flush: each lane writes one query's 256B contiguous run.
__global__ __launch_bounds__(64) void k_samp(
    const short* __restrict__ Xh, const short* __restrict__ Qh,
    const float* __restrict__ x2, unsigned short* __restrict__ keys) {
    int bid = blockIdx.x;
    int qt = bid & 7;
    int rb = bid >> 3;          // 0..63
    int lane = threadIdx.x;
    int lr = lane & 15;
    int lk = lane >> 4;

    __shared__ unsigned short skey[128 * 132];   // 33.8 KB

    int r0 = rb << 7;           // 128 rows per block
    int qbase = qt << 7;

    f16x8 afr[8][2];
#pragma unroll
    for (int qi = 0; qi < 8; qi++) {
        const short* qp = Qh + (long)(qbase + (qi << 4) + lr) * 64 + (lk << 3);
        afr[qi][0] = *(const f16x8*)qp;
        afr[qi][1] = *(const f16x8*)(qp + 32);
    }

    // depth-1 register prefetch over 16-row groups (all rows valid)
    f16x8 cb0, cb1;
    float cx2;
    {
        const short* xp = Xh + (long)(r0 + lr) * 64 + (lk << 3);
        cb0 = *(const f16x8*)xp;
        cb1 = *(const f16x8*)(xp + 32);
        cx2 = x2[r0 + lr];
    }

#pragma unroll 1
    for (int g = 0; g < 8; g++) {
        f16x8 b0 = cb0, b1 = cb1;
        float x2c = cx2;
        if (g < 7) {
            int nr = r0 + ((g + 1) << 4) + lr;
            const short* xp = Xh + (long)nr * 64 + (lk << 3);
            cb0 = *(const f16x8*)xp;
            cb1 = *(const f16x8*)(xp + 32);
            cx2 = x2[nr];
        }
        int lrow = (g << 4) + lr;   // local row 0..127

#pragma unroll
        for (int qi = 0; qi < 8; qi++) {
            f32x4 acc = {0.f, 0.f, 0.f, 0.f};
            acc = __builtin_amdgcn_mfma_f32_16x16x32_f16(afr[qi][0], b0, acc, 0, 0, 0);
            acc = __builtin_amdgcn_mfma_f32_16x16x32_f16(afr[qi][1], b1, acc, 0, 0, 0);
#pragma unroll
            for (int r4 = 0; r4 < 4; r4++) {
                unsigned k16 = fmap(x2c - 2.f * acc[r4]) >> 16;
                int ql = (qi << 4) + (lk << 2) + r4;     // 0..127
                skey[ql * 132 + lrow] = (unsigned short)k16;
            }
        }
    }

    __syncthreads();
    // flush: lane -> query; 256B contiguous per query (16 x uint4)
#pragma unroll
    for (int j = 0; j < 2; j++) {
        int q = (j << 6) + lane;
        long gb = ((long)(qbase + q) << 13) + r0;     // element index
#pragma unroll
        for (int w = 0; w < 16; w++) {
            const unsigned* sp = (const unsigned*)&skey[q * 132 + (w << 3)];
            uint4 v = make_uint4(sp[0], sp[1], sp[2], sp[3]);
            *(uint4*)&keys[gb + (w << 3)] = v;
        }
    }
}

// ---------------- 32nd-smallest sample key -> widened threshold (f16 bound)
__global__ __launch_bounds__(256) void k_sel(const unsigned short* __restrict__ keys,
                                             const float* __restrict__ Qm,
                                             const float* __restrict__ x2maxf,
                                             float* __restrict__ tqw,
                                             float* __restrict__ q2g) {
    int q = blockIdx.x, tid = threadIdx.x;
    unsigned short mk[32];
#pragma unroll
    for (int m = 0; m < 32; m++) mk[m] = keys[(long)q * SAMPLES + tid + 256 * m];
    __shared__ float q2s_;
    __shared__ int cnt;
    if (tid < 64) {
        float v = Qm[(long)q * 64 + tid];
        float p = v * v;
#pragma unroll
        for (int d = 1; d < 64; d <<= 1) p += __shfl_xor(p, d);
        if (tid == 0) q2s_ = p;
    }
    unsigned lo = 0, hi = 65535;
    for (int it = 0; it < 16; ++it) {
        __syncthreads();
        if (tid == 0) cnt = 0;
        __syncthreads();
        unsigned mid = (lo + hi) >> 1;
        int c = 0;
#pragma unroll
        for (int m = 0; m < 32; m++) c += (mk[m] <= mid) ? 1 : 0;
#pragma unroll
        for (int d = 1; d < 64; d <<= 1) c += __shfl_xor(c, d);
        if ((tid & 63) == 0) atomicAdd(&cnt, c);
        __syncthreads();
        if (cnt >= KSEL) hi = mid; else lo = mid + 1;
    }
    if (tid == 0) {
        unsigned vv = hi + 2u; if (vv > 65535u) vv = 65535u;
        float t = funmap(vv << 16);
        float q2 = q2s_;
        // widen: 2x f16 dot-error bound + margin
        tqw[q] = t + 0.004f * sqrtf(q2 * (*x2maxf)) + 0.1f;
        q2g[q] = q2;
    }
}

// ================================================================ k_dist
// Filter pass (R13, proven 128us): single-wave blocks, XCD-aware mapping,
// 128 queries/wave, depth-1 register prefetch, LDS pools -> sentinel flush.
__global__ __launch_bounds__(64) void k_dist(
    const short* __restrict__ Xh, const short* __restrict__ Qh,
    const float* __restrict__ x2, const float* __restrict__ tqw,
    unsigned* __restrict__ pool,
    unsigned* __restrict__ ovfcnt, uint2* __restrict__ ovf) {
    int bid = blockIdx.x;
    int xcd = bid & 7;
    int j = bid >> 3;
    int cb = xcd * 131 + (j >> 3);
    int qt = j & 7;
    int lane = threadIdx.x;     // 0..63
    int lr = lane & 15;
    int lk = lane >> 4;

    __shared__ unsigned lcnt[128];
    __shared__ unsigned lbuf[128 * LCAP];

    int r0 = cb * CHR;
    int rowEnd = min(r0 + CHR, N_TRAIN);

    lcnt[lane] = 0u;
    lcnt[lane + 64] = 0u;
    __syncthreads();

    int qbase = qt << 7;        // 128 queries

    f16x8 afr[8][2];
#pragma unroll
    for (int qi = 0; qi < 8; qi++) {
        const short* qp = Qh + (long)(qbase + (qi << 4) + lr) * 64 + (lk << 3);
        afr[qi][0] = *(const f16x8*)qp;
        afr[qi][1] = *(const f16x8*)(qp + 32);
    }
    float htq[8];
#pragma unroll
    for (int qi = 0; qi < 8; qi++) {
        float4 t4 = *(const float4*)(tqw + qbase + (qi << 4) + (lk << 2));
        htq[qi] = 0.5f * fmaxf(fmaxf(t4.x, t4.y), fmaxf(t4.z, t4.w));
    }

    // depth-1 register prefetch over 16-row groups
    f16x8 cb0, cb1;
    float cx2;
    {
        int rowc = min(r0 + lr, rowEnd - 1);
        const short* xp = Xh + (long)rowc * 64 + (lk << 3);
        cb0 = *(const f16x8*)xp;
        cb1 = *(const f16x8*)(xp + 32);
        cx2 = (r0 + lr < rowEnd) ? x2[rowc] : 1e30f;
    }

    for (int base = r0; base < rowEnd; base += 16) {
        f16x8 b0 = cb0, b1 = cb1;
        float x2c = cx2;
        int nb = base + 16;
        if (nb < rowEnd) {                       // issue next group's loads now
            int rowc = min(nb + lr, rowEnd - 1);
            const short* xp = Xh + (long)rowc * 64 + (lk << 3);
            cb0 = *(const f16x8*)xp;
            cb1 = *(const f16x8*)(xp + 32);
            cx2 = (nb + lr < rowEnd) ? x2[rowc] : 1e30f;
        }
        int row = base + lr;
        bool valid = row < rowEnd;
        float hx = 0.5f * x2c;

#pragma unroll
        for (int qi = 0; qi < 8; qi++) {
            f32x4 acc = {0.f, 0.f, 0.f, 0.f};
            acc = __builtin_amdgcn_mfma_f32_16x16x32_f16(afr[qi][0], b0, acc, 0, 0, 0);
            acc = __builtin_amdgcn_mfma_f32_16x16x32_f16(afr[qi][1], b1, acc, 0, 0, 0);
            float mx = fmaxf(fmaxf(acc[0], acc[1]), fmaxf(acc[2], acc[3]));
            if (valid && mx >= hx - htq[qi]) {     // sound quick reject
                float4 t4 = *(const float4*)(tqw + qbase + (qi << 4) + (lk << 2));
                float tq4[4] = {t4.x, t4.y, t4.z, t4.w};
#pragma unroll
                for (int r4 = 0; r4 < 4; r4++) {
                    if (acc[r4] >= hx - 0.5f * tq4[r4]) {
                        int ql = (qi << 4) + (lk << 2) + r4;     // 0..127
                        int qg = qbase + ql;
                        // 24-bit approx key + 8-bit local row (<192)
                        unsigned entry = (fmap(x2c - 2.f * acc[r4]) & 0xFFFFFF00u) |
                                         (unsigned)(row - r0);
                        unsigned slot = atomicAdd(&lcnt[ql], 1u);
                        if (slot < LCAP) {
                            lbuf[ql * LCAP + slot] = entry;
                        } else {   // rare overflow: per-query global pool
                            unsigned o = atomicAdd(&ovfcnt[qg], 1u);
                            if (o < OVFCAP)
                                ovf[qg * OVFCAP + o] =
                                    make_uint2(entry >> 8, (unsigned)row);
                        }
                    }
                }
            }
        }
    }

    // sentinel-coded flush: one uint4 per query, no global atomics
    __syncthreads();
#pragma unroll
    for (int j2 = 0; j2 < 2; j2++) {
        int ql = (j2 << 6) + lane;
        unsigned lc = min(lcnt[ql], (unsigned)LCAP);
        uint4 v;
        v.x = (lc > 0) ? lbuf[ql * LCAP + 0] : SENT;
        v.y = (lc > 1) ? lbuf[ql * LCAP + 1] : SENT;
        v.z = (lc > 2) ? lbuf[ql * LCAP + 2] : SENT;
        v.w = (lc > 3) ? lbuf[ql * LCAP + 3] : SENT;
        *(uint4*)&pool[((long)cb * NQ + qbase + ql) * LCAP] = v;
    }
}

// ---------------- approx-cut (24-bit) -> exact re-rank survivors -> vote
__global__ __launch_bounds__(256) void k_merge(const float* __restrict__ Qm,
                                               const float* __restrict__ X,
                                               const float* __restrict__ x2,
                                               const int* __restrict__ labels,
                                               const unsigned* __restrict__ pool,
                                               const unsigned* __restrict__ ovfcnt,
                                               const uint2* __restrict__ ovf,
                                               const float* __restrict__ q2g,
                                               const float* __restrict__ x2maxf,
                                               int* __restrict__ out) {
    int q = blockIdx.x, tid = threadIdx.x;
    __shared__ unsigned eK[TOTC];        // 24-bit approx keys
    __shared__ int eR[TOTC];
    __shared__ int sR[MAXS];
    __shared__ float sKey[MAXS];
    __shared__ int sLab[MAXS];
    __shared__ float qs[64];
    __shared__ int tot, cnt, ns, nw, nt;
    __shared__ unsigned cutS;
    __shared__ float wKey[34];
    __shared__ int wLab[34];
    __shared__ int tIdx[64];
    __shared__ int tLab[64];

    if (tid == 0) { tot = 0; ns = 0; nw = 0; nt = 0; }
    if (tid < 64) qs[tid] = Qm[(long)q * 64 + tid];
    __syncthreads();

    // gather from sentinel-coded pools
    for (int c2 = tid; c2 < NCH; c2 += 256) {
        uint4 v = *(const uint4*)&pool[((long)c2 * NQ + q) * LCAP];
        int rbase = c2 * CHR;
        if (v.x != SENT) { int p = atomicAdd(&tot, 1); if (p < TOTC) { eK[p] = v.x >> 8; eR[p] = rbase + (int)(v.x & 255u); } }
        if (v.y != SENT) { int p = atomicAdd(&tot, 1); if (p < TOTC) { eK[p] = v.y >> 8; eR[p] = rbase + (int)(v.y & 255u); } }
        if (v.z != SENT) { int p = atomicAdd(&tot, 1); if (p < TOTC) { eK[p] = v.z >> 8; eR[p] = rbase + (int)(v.z & 255u); } }
        if (v.w != SENT) { int p = atomicAdd(&tot, 1); if (p < TOTC) { eK[p] = v.w >> 8; eR[p] = rbase + (int)(v.w & 255u); } }
    }
    int ov = min((int)ovfcnt[q], OVFCAP);
    for (int i = tid; i < ov; i += 256) {
        uint2 e = ovf[q * OVFCAP + i];
        int p = atomicAdd(&tot, 1);
        if (p < TOTC) { eK[p] = e.x; eR[p] = (int)e.y; }
    }
    __syncthreads();
    int T = min(tot, TOTC);

    // bisect 24-bit approx keys for the 32nd smallest
    unsigned mk[16];
#pragma unroll
    for (int m = 0; m < 16; m++) { int i = tid + (m << 8); mk[m] = (i < T) ? eK[i] : 0xFFFFFFFFu; }
    unsigned lo = 0, hi = 0xFFFFFFu;
    for (int it = 0; it < 24; ++it) {
        __syncthreads();
        if (tid == 0) cnt = 0;
        __syncthreads();
        unsigned mid = (lo + hi) >> 1;
        int c = 0;
#pragma unroll
        for (int m = 0; m < 16; m++) c += (mk[m] <= mid) ? 1 : 0;
#pragma unroll
        for (int d = 1; d < 64; d <<= 1) c += __shfl_xor(c, d);
        if ((tid & 63) == 0) atomicAdd(&cnt, c);
        __syncthreads();
        if (cnt >= KSEL) hi = mid; else lo = mid + 1;
    }
    float q2v = q2g[q];
    if (tid == 0) {
        unsigned vv = min(hi + 1u, 0xFFFFFFu);
        float tf = funmap(vv << 8);
        float err = 0.004f * sqrtf(q2v * (*x2maxf)) + 0.1f;   // 2x f16 key error + margin
        cutS = min((fmap(tf + err) >> 8) + 1u, 0xFFFFFFu);
    }
    __syncthreads();
    unsigned cut = cutS;
    for (int i = tid; i < T; i += 256)
        if (eK[i] <= cut) { int p = atomicAdd(&ns, 1); if (p < MAXS) sR[p] = eR[i]; }
    __syncthreads();
    int NS = min(ns, MAXS);

    // exact fp32 re-rank of survivors
    for (int i = tid; i < NS; i += 256) {
        int row = sR[i];
        const float4* xr = (const float4*)(X + (long)row * 64);
        const float4* qr = (const float4*)qs;
        float dot = 0.f;
#pragma unroll
        for (int k4 = 0; k4 < 16; k4++) {
            float4 xv = xr[k4], qv = qr[k4];
            dot += qv.x * xv.x + qv.y * xv.y + qv.z * xv.z + qv.w * xv.w;
        }
        sKey[i] = x2[row] - 2.f * dot;
        sLab[i] = labels[row];
    }
    __syncthreads();

    // exact 32nd smallest among survivors (32-step bisection)
    unsigned uk[6];
#pragma unroll
    for (int m = 0; m < 6; m++) { int i = tid + (m << 8); uk[m] = (i < NS) ? fmap(sKey[i]) : 0xFFFFFFFFu; }
    unsigned lo2 = 0u, hi2 = 0xFFFFFFFFu;
    for (int it = 0; it < 32; ++it) {
        __syncthreads();
        if (tid == 0) cnt = 0;
        __syncthreads();
        unsigned mid = lo2 + ((hi2 - lo2) >> 1);
        int c = 0;
#pragma unroll
        for (int m = 0; m < 6; m++) c += (uk[m] <= mid) ? 1 : 0;
#pragma unroll
        for (int d = 1; d < 64; d <<= 1) c += __shfl_xor(c, d);
        if ((tid & 63) == 0) atomicAdd(&cnt, c);
        __syncthreads();
        if (cnt >= KSEL) hi2 = mid; else lo2 = mid + 1;
    }
    unsigned T32 = hi2;   // count(<T32) <= 31, count(<=T32) >= 32

#pragma unroll
    for (int m = 0; m < 6; m++) {
        int i = tid + (m << 8);
        if (i < NS) {
            if (uk[m] < T32) {
                int p = atomicAdd(&nw, 1);
                if (p < 34) { wKey[p] = sKey[i]; wLab[p] = sLab[i]; }
            } else if (uk[m] == T32) {
                int p = atomicAdd(&nt, 1);
                if (p < 64) { tIdx[p] = sR[i]; tLab[p] = sLab[i]; }
            }
        }
    }
    __syncthreads();

    if (tid == 0) {
        float votes[NCLS] = {0.f, 0.f, 0.f, 0.f, 0.f, 0.f, 0.f, 0.f, 0.f, 0.f};
        int NW = min(nw, 32);
        for (int i = 0; i < NW; i++) {
            float dist = q2v + wKey[i];
            if (dist < 0.f) dist = 0.f;
            if (dist == 0.f) dist = 0.1f;
            votes[wLab[i]] += 1.f / dist;
        }
        int need = KSEL - NW;
        int NT = min(nt, 64);
        float tkey = funmap(T32);
        float dist = q2v + tkey;
        if (dist < 0.f) dist = 0.f;
        if (dist == 0.f) dist = 0.1f;
        float twgt = 1.f / dist;
        for (int t = 0; t < need && t < NT; t++) {   // ties: smallest index first
            int best = -1, bi = 0x7FFFFFFF;
            for (int u = 0; u < NT; u++)
                if (tIdx[u] < bi) { bi = tIdx[u]; best = u; }
            if (best < 0) break;
            votes[tLab[best]] += twgt;
            tIdx[best] = 0x7FFFFFFF;
        }
        float bv = votes[0];
        int bc = 0;
#pragma unroll
        for (int c = 1; c < NCLS; c++)
            if (votes[c] > bv) { bv = votes[c]; bc = c; }
        out[q] = bc;
    }
}

extern "C" void kernel_launch(void* const* d_in, const int* in_sizes, int n_in,
                              void* d_out, int out_size, void* d_ws, size_t ws_size,
                              hipStream_t stream) {
    const float* Qm = (const float*)d_in[0];
    const float* X = (const float*)d_in[1];
    const int* labels = (const int*)d_in[2];
    char* ws = (char*)d_ws;
    // ws layout (end = 45,823,552 B; proven ws_size >= 52,017,408):
    // [0,800000)            x2     float[200000]
    // [800000,804096)       tqw    float[1024]
    // [804096,808192)       q2g    float[1024]
    // [808192,808196)       x2maxf float
    // [808256,820756)       bmax   float[3125]
    // [820800,824896)       ovfcnt u32[1024]
    // [824896,2922048)      ovf    uint2[1024*256]
    // [2922048,20092480)    pool u32[1048*1024*4] ALIASED WITH keys u16[1024*8192]
    // [20092480,45692480)   Xh f16[200000*64]
    // [45692480,45823552)   Qh f16[1024*64]
    float* x2 = (float*)(ws + 0);
    float* tqw = (float*)(ws + 800000);
    float* q2g = (float*)(ws + 804096);
    float* x2maxf = (float*)(ws + 808192);
    float* bmax = (float*)(ws + 808256);
    unsigned* ovfcnt = (unsigned*)(ws + 820800);
    uint2* ovf = (uint2*)(ws + 824896);
    unsigned* pool = (unsigned*)(ws + 2922048);
    unsigned short* keys = (unsigned short*)(ws + 2922048);
    short* Xh = (short*)(ws + 20092480);
    short* Qh = (short*)(ws + 45692480);
    int* out = (int*)d_out;

    hipMemsetAsync(ovfcnt, 0, 4096, stream);
    k_prep<<<NPB, 512, 0, stream>>>(X, x2, bmax, Xh);
    k_max<<<1, 256, 0, stream>>>(bmax, x2maxf);
    k_cvt<<<32, 256, 0, stream>>>(Qm, Qh);
    k_samp<<<512, 64, 0, stream>>>(Xh, Qh, x2, keys);
    k_sel<<<NQ, 256, 0, stream>>>(keys, Qm, x2maxf, tqw, q2g);
    k_dist<<<8 * NCH, 64, 0, stream>>>(Xh, Qh, x2, tqw, pool, ovfcnt, ovf);
    k_merge<<<NQ, 256, 0, stream>>>(Qm, X, x2, labels, pool, ovfcnt, ovf, q2g, x2maxf, out);
}